// Round 1
// baseline (211.267 us; speedup 1.0000x reference)
//
#include <hip/hip_runtime.h>
#include <stdint.h>

typedef float f32x4 __attribute__((ext_vector_type(4)));
typedef __bf16 bf16x8 __attribute__((ext_vector_type(8)));
typedef unsigned int u32x4 __attribute__((ext_vector_type(4)));
typedef unsigned short u16x4 __attribute__((ext_vector_type(4)));
typedef unsigned short u16x8 __attribute__((ext_vector_type(8)));

#define DEV __device__ __forceinline__

// round-to-nearest-even f32 -> bf16 bits
DEV unsigned short f2bf(float f) {
    unsigned u = __builtin_bit_cast(unsigned, f);
    u += 0x7fffu + ((u >> 16) & 1u);
    return (unsigned short)(u >> 16);
}

// async global->LDS, 16B per lane. LDS dst must be wave-uniform-base + lane*16.
DEV void gload16(const void* g, void* l) {
    __builtin_amdgcn_global_load_lds(
        (const __attribute__((address_space(1))) unsigned int*)(uintptr_t)g,
        (__attribute__((address_space(3))) unsigned int*)(unsigned int)(uintptr_t)l,
        16, 0, 0);
}

// ---------------- fp32 -> bf16 elementwise ----------------
__global__ void k_cvt(const float* __restrict__ in, unsigned short* __restrict__ out, int n4) {
    int i = blockIdx.x * 256 + threadIdx.x;
    int st = gridDim.x * 256;
    for (; i < n4; i += st) {
        f32x4 v = *(const f32x4*)(in + (size_t)i * 4);
        u16x4 o;
        o[0] = f2bf(v[0]); o[1] = f2bf(v[1]); o[2] = f2bf(v[2]); o[3] = f2bf(v[3]);
        *(u16x4*)(out + (size_t)i * 4) = o;
    }
}

// ---------------- fp32 [1024][Nc] -> bf16 [Nc][1024] transpose ----------------
__global__ void k_transpose(const float* __restrict__ in, unsigned short* __restrict__ out, int Nc) {
    __shared__ unsigned short tl[64][68];
    int n0 = blockIdx.x * 64, k0 = blockIdx.y * 64;
#pragma unroll
    for (int i = 0; i < 16; i++) {
        int idx = i * 256 + threadIdx.x;
        int kr = idx >> 6, nc = idx & 63;
        tl[kr][nc] = f2bf(in[(size_t)(k0 + kr) * Nc + n0 + nc]);
    }
    __syncthreads();
#pragma unroll
    for (int i = 0; i < 8; i++) {
        int idx = i * 256 + threadIdx.x;
        int nr = idx >> 5, kp2 = idx & 31;
        unsigned vv = (unsigned)tl[kp2 * 2][nr] | ((unsigned)tl[kp2 * 2 + 1][nr] << 16);
        *(unsigned*)(out + (size_t)(n0 + nr) * 1024 + k0 + kp2 * 2) = vv;
    }
}

// ---------------- GEMM: C[M][N] = A[M][K] * Bt[N][K]^T  (bf16 in, fp32 acc) ----
// MODE 1: scatter to q/k/v [B][H][N][D] bf16 (q scaled by 0.125)
// MODE 3: out fp32 = C + bias (N fixed 1024)
template <int MODE>
__global__ __launch_bounds__(256) void k_gemm(
    const unsigned short* __restrict__ A, const unsigned short* __restrict__ Bt, int K,
    unsigned short* __restrict__ q, unsigned short* __restrict__ kk_,
    unsigned short* __restrict__ v, const float* __restrict__ bias,
    float* __restrict__ outf) {
    __shared__ unsigned short As[128 * 64];
    __shared__ unsigned short Bs[128 * 64];
    const int tid = threadIdx.x;
    const int w = tid >> 6, l = tid & 63, g = l >> 4, lr = l & 15;
    const int wr = w >> 1, wc = w & 1;
    const int m0 = blockIdx.y * 128, n0 = blockIdx.x * 128;
    f32x4 acc[4][4] = {};

    for (int k0 = 0; k0 < K; k0 += 64) {
        __syncthreads();
#pragma unroll
        for (int i = 0; i < 4; i++) {
            int c = i * 256 + tid;
            gload16(A + (size_t)(m0 + (c >> 3)) * K + k0 + (c & 7) * 8, (char*)As + c * 16);
            gload16(Bt + (size_t)(n0 + (c >> 3)) * K + k0 + (c & 7) * 8, (char*)Bs + c * 16);
        }
        __syncthreads();
#pragma unroll
        for (int kk = 0; kk < 2; kk++) {
            bf16x8 af[4], bfv[4];
#pragma unroll
            for (int mi = 0; mi < 4; mi++)
                af[mi] = *(const bf16x8*)(As + (wr * 64 + mi * 16 + lr) * 64 + kk * 32 + g * 8);
#pragma unroll
            for (int ni = 0; ni < 4; ni++)
                bfv[ni] = *(const bf16x8*)(Bs + (wc * 64 + ni * 16 + lr) * 64 + kk * 32 + g * 8);
#pragma unroll
            for (int mi = 0; mi < 4; mi++)
#pragma unroll
                for (int ni = 0; ni < 4; ni++)
                    acc[mi][ni] = __builtin_amdgcn_mfma_f32_16x16x32_bf16(af[mi], bfv[ni], acc[mi][ni], 0, 0, 0);
        }
    }

#pragma unroll
    for (int mi = 0; mi < 4; mi++) {
#pragma unroll
        for (int ni = 0; ni < 4; ni++) {
#pragma unroll
            for (int r = 0; r < 4; r++) {
                int row = m0 + wr * 64 + mi * 16 + g * 4 + r;
                int col = n0 + wc * 64 + ni * 16 + lr;
                float val = acc[mi][ni][r];
                if (MODE == 1) {
                    int b = row >> 11, n = row & 2047;
                    int which = col >> 10, cc = col & 1023;
                    int h = cc >> 6, d = cc & 63;
                    unsigned short* dst = which == 0 ? q : (which == 1 ? kk_ : v);
                    if (which == 0) val *= 0.125f;  // SCALE = 64^-0.5
                    dst[((size_t)(b * 16 + h) * 2048 + n) * 64 + d] = f2bf(val);
                } else {
                    outf[(size_t)row * 1024 + col] = val + bias[col];
                }
            }
        }
    }
}

// ---------------- flash attention: per (b,h), 4 waves x 16 q-rows, KV tile 64 --
__global__ __launch_bounds__(256) void k_attn(
    const unsigned short* __restrict__ qb, const unsigned short* __restrict__ kb,
    const unsigned short* __restrict__ vb, unsigned short* __restrict__ ao) {
    __shared__ unsigned short Ks[64][72];      // [kv][d], +8 pad
    __shared__ unsigned short Vt[64][72];      // [d][kv], +8 pad
    __shared__ unsigned short Ps[4][16][72];   // per-wave P tile
    const int tid = threadIdx.x;
    const int w = tid >> 6, l = tid & 63, g = l >> 4, lr = l & 15;
    const int bh = blockIdx.y, b = bh >> 4, h = bh & 15;
    const int q0 = blockIdx.x * 64 + w * 16;
    const unsigned short* qp = qb + (size_t)bh * 131072;
    const unsigned short* kp = kb + (size_t)bh * 131072;
    const unsigned short* vp = vb + (size_t)bh * 131072;

    bf16x8 qf[2];
#pragma unroll
    for (int kk = 0; kk < 2; kk++)
        qf[kk] = *(const bf16x8*)(qp + (q0 + lr) * 64 + kk * 32 + g * 8);

    f32x4 o_acc[4] = {};
    float m_r[4], l_r[4];
#pragma unroll
    for (int r = 0; r < 4; r++) { m_r[r] = -1e30f; l_r[r] = 0.f; }

    for (int kv0 = 0; kv0 < 2048; kv0 += 64) {
        __syncthreads();
        // stage K rows (vector LDS writes, even banks)
#pragma unroll
        for (int i = 0; i < 2; i++) {
            int idx = i * 256 + tid;
            int row = idx >> 3, cg = idx & 7;
            *(u32x4*)&Ks[row][cg * 8] = *(const u32x4*)(kp + (kv0 + row) * 64 + cg * 8);
        }
        // stage V transposed: coalesced u16 row-loads, one b128 LDS write per task
#pragma unroll
        for (int i = 0; i < 2; i++) {
            int j0 = (w + i * 4) * 8;
            u16x8 tv;
#pragma unroll
            for (int jj = 0; jj < 8; jj++)
                tv[jj] = vp[(kv0 + j0 + jj) * 64 + l];
            *(u16x8*)&Vt[l][j0] = tv;
        }
        __syncthreads();

        // S = Q K^T  (q pre-scaled by 0.125 in GEMM1 epilogue)
        f32x4 s_acc[4];
#pragma unroll
        for (int ct = 0; ct < 4; ct++) s_acc[ct] = (f32x4){0.f, 0.f, 0.f, 0.f};
#pragma unroll
        for (int kk = 0; kk < 2; kk++) {
#pragma unroll
            for (int ct = 0; ct < 4; ct++) {
                bf16x8 kf = *(const bf16x8*)&Ks[ct * 16 + lr][kk * 32 + g * 8];
                s_acc[ct] = __builtin_amdgcn_mfma_f32_16x16x32_bf16(qf[kk], kf, s_acc[ct], 0, 0, 0);
            }
        }

        // online softmax (rows 4g+r live across the 16 lanes lr of this group)
        float fac[4];
#pragma unroll
        for (int r = 0; r < 4; r++) {
            float mx = fmaxf(fmaxf(s_acc[0][r], s_acc[1][r]), fmaxf(s_acc[2][r], s_acc[3][r]));
            mx = fmaxf(mx, __shfl_xor(mx, 1, 16));
            mx = fmaxf(mx, __shfl_xor(mx, 2, 16));
            mx = fmaxf(mx, __shfl_xor(mx, 4, 16));
            mx = fmaxf(mx, __shfl_xor(mx, 8, 16));
            float mn = fmaxf(m_r[r], mx);
            fac[r] = __expf(m_r[r] - mn);
            m_r[r] = mn;
        }
#pragma unroll
        for (int ct = 0; ct < 4; ct++) {
#pragma unroll
            for (int r = 0; r < 4; r++) {
                float p = __expf(s_acc[ct][r] - m_r[r]);
                s_acc[ct][r] = p;
                Ps[w][g * 4 + r][ct * 16 + lr] = f2bf(p);
            }
        }
#pragma unroll
        for (int r = 0; r < 4; r++) {
            float s = s_acc[0][r] + s_acc[1][r] + s_acc[2][r] + s_acc[3][r];
            s += __shfl_xor(s, 1, 16);
            s += __shfl_xor(s, 2, 16);
            s += __shfl_xor(s, 4, 16);
            s += __shfl_xor(s, 8, 16);
            l_r[r] = l_r[r] * fac[r] + s;
            o_acc[0][r] *= fac[r]; o_acc[1][r] *= fac[r];
            o_acc[2][r] *= fac[r]; o_acc[3][r] *= fac[r];
        }
        // fence Ps writes before Ps fragment reads (same wave; rule #18)
        asm volatile("s_waitcnt lgkmcnt(0)" ::: "memory");
        __builtin_amdgcn_sched_barrier(0);

        // O += P V
#pragma unroll
        for (int kk = 0; kk < 2; kk++) {
            bf16x8 pf = *(const bf16x8*)&Ps[w][lr][kk * 32 + g * 8];
#pragma unroll
            for (int ct = 0; ct < 4; ct++) {
                bf16x8 vf = *(const bf16x8*)&Vt[ct * 16 + lr][kk * 32 + g * 8];
                o_acc[ct] = __builtin_amdgcn_mfma_f32_16x16x32_bf16(pf, vf, o_acc[ct], 0, 0, 0);
            }
        }
    }

#pragma unroll
    for (int ct = 0; ct < 4; ct++) {
#pragma unroll
        for (int r = 0; r < 4; r++) {
            float o = o_acc[ct][r] / l_r[r];
            int qrow = q0 + g * 4 + r;
            ao[((size_t)b * 2048 + qrow) * 1024 + h * 64 + ct * 16 + lr] = f2bf(o);
        }
    }
}

extern "C" void kernel_launch(void* const* d_in, const int* in_sizes, int n_in,
                              void* d_out, int out_size, void* d_ws, size_t ws_size,
                              hipStream_t stream) {
    (void)in_sizes; (void)n_in; (void)out_size; (void)ws_size;
    const float* x      = (const float*)d_in[0];
    const float* w_qkv  = (const float*)d_in[1];
    const float* w_proj = (const float*)d_in[2];
    const float* b_proj = (const float*)d_in[3];
    float* out = (float*)d_out;
    char* ws = (char*)d_ws;

    // workspace layout (bytes); ao aliases xb (xb dead after GEMM1)
    unsigned short* xb     = (unsigned short*)(ws);             // [4096][1024] bf16
    unsigned short* ao     = (unsigned short*)(ws);             // [4096][1024] bf16 (alias)
    unsigned short* wqkvT  = (unsigned short*)(ws + 8388608);   // [3072][1024] bf16
    unsigned short* wprojT = (unsigned short*)(ws + 14680064);  // [1024][1024] bf16
    unsigned short* qb     = (unsigned short*)(ws + 16777216);  // [2][16][2048][64] bf16
    unsigned short* kb     = (unsigned short*)(ws + 25165824);
    unsigned short* vb     = (unsigned short*)(ws + 33554432);

    k_cvt<<<2048, 256, 0, stream>>>(x, xb, 1048576);
    k_transpose<<<dim3(48, 16), 256, 0, stream>>>(w_qkv, wqkvT, 3072);
    k_transpose<<<dim3(16, 16), 256, 0, stream>>>(w_proj, wprojT, 1024);
    k_gemm<1><<<dim3(24, 32), 256, 0, stream>>>(xb, wqkvT, 1024, qb, kb, vb, nullptr, nullptr);
    k_attn<<<dim3(32, 32), 256, 0, stream>>>(qb, kb, vb, ao);
    k_gemm<3><<<dim3(8, 32), 256, 0, stream>>>(ao, wprojT, 1024, nullptr, nullptr, nullptr, b_proj, out);
}

// Round 3
// 172.442 us; speedup vs baseline: 1.2251x; 1.2251x over previous
//
#include <hip/hip_runtime.h>
#include <stdint.h>

typedef float f32x4 __attribute__((ext_vector_type(4)));
typedef __bf16 bf16x8 __attribute__((ext_vector_type(8)));
typedef unsigned int u32x4 __attribute__((ext_vector_type(4)));
typedef unsigned int u32x2 __attribute__((ext_vector_type(2)));
typedef unsigned short u16x4 __attribute__((ext_vector_type(4)));
typedef unsigned short u16x8 __attribute__((ext_vector_type(8)));

#define DEV __device__ __forceinline__

// round-to-nearest-even f32 -> bf16 bits
DEV unsigned short f2bf(float f) {
    unsigned u = __builtin_bit_cast(unsigned, f);
    u += 0x7fffu + ((u >> 16) & 1u);
    return (unsigned short)(u >> 16);
}

DEV unsigned pack2bf(float a, float b) {
    return (unsigned)f2bf(a) | ((unsigned)f2bf(b) << 16);
}

// async global->LDS, 16B per lane. LDS dst must be wave-uniform-base + lane*16.
DEV void gload16(const void* g, void* l) {
    __builtin_amdgcn_global_load_lds(
        (const __attribute__((address_space(1))) unsigned int*)(uintptr_t)g,
        (__attribute__((address_space(3))) unsigned int*)(unsigned int)(uintptr_t)l,
        16, 0, 0);
}

// ---------------- fp32 -> bf16 elementwise ----------------
__global__ void k_cvt(const float* __restrict__ in, unsigned short* __restrict__ out, int n4) {
    int i = blockIdx.x * 256 + threadIdx.x;
    int st = gridDim.x * 256;
    for (; i < n4; i += st) {
        f32x4 v = *(const f32x4*)(in + (size_t)i * 4);
        u16x4 o;
        o[0] = f2bf(v[0]); o[1] = f2bf(v[1]); o[2] = f2bf(v[2]); o[3] = f2bf(v[3]);
        *(u16x4*)(out + (size_t)i * 4) = o;
    }
}

// ---------------- fp32 [1024][Nc] -> bf16 [Nc][1024] transpose ----------------
__global__ void k_transpose(const float* __restrict__ in, unsigned short* __restrict__ out, int Nc) {
    __shared__ unsigned short tl[64][68];
    int n0 = blockIdx.x * 64, k0 = blockIdx.y * 64;
#pragma unroll
    for (int i = 0; i < 16; i++) {
        int idx = i * 256 + threadIdx.x;
        int kr = idx >> 6, nc = idx & 63;
        tl[kr][nc] = f2bf(in[(size_t)(k0 + kr) * Nc + n0 + nc]);
    }
    __syncthreads();
#pragma unroll
    for (int i = 0; i < 8; i++) {
        int idx = i * 256 + threadIdx.x;
        int nr = idx >> 5, kp2 = idx & 31;
        unsigned vv = (unsigned)tl[kp2 * 2][nr] | ((unsigned)tl[kp2 * 2 + 1][nr] << 16);
        *(unsigned*)(out + (size_t)(n0 + nr) * 1024 + k0 + kp2 * 2) = vv;
    }
}

// ---------------- GEMM: C[M][N] = A[M][K] * Bt[N][K]^T  (bf16 in, fp32 acc) ----
// MODE 1: scatter to q/k/v [B][H][N][D] bf16 (q scaled by 0.125)
// MODE 3: out fp32 = C + bias (N fixed 1024)
template <int MODE>
__global__ __launch_bounds__(256) void k_gemm(
    const unsigned short* __restrict__ A, const unsigned short* __restrict__ Bt, int K,
    unsigned short* __restrict__ q, unsigned short* __restrict__ kk_,
    unsigned short* __restrict__ v, const float* __restrict__ bias,
    float* __restrict__ outf) {
    __shared__ unsigned short As[128 * 64];
    __shared__ unsigned short Bs[128 * 64];
    const int tid = threadIdx.x;
    const int w = tid >> 6, l = tid & 63, g = l >> 4, lr = l & 15;
    const int wr = w >> 1, wc = w & 1;
    const int m0 = blockIdx.y * 128, n0 = blockIdx.x * 128;
    f32x4 acc[4][4] = {};

    for (int k0 = 0; k0 < K; k0 += 64) {
        __syncthreads();
#pragma unroll
        for (int i = 0; i < 4; i++) {
            int c = i * 256 + tid;
            gload16(A + (size_t)(m0 + (c >> 3)) * K + k0 + (c & 7) * 8, (char*)As + c * 16);
            gload16(Bt + (size_t)(n0 + (c >> 3)) * K + k0 + (c & 7) * 8, (char*)Bs + c * 16);
        }
        __syncthreads();
#pragma unroll
        for (int kk = 0; kk < 2; kk++) {
            bf16x8 af[4], bfv[4];
#pragma unroll
            for (int mi = 0; mi < 4; mi++)
                af[mi] = *(const bf16x8*)(As + (wr * 64 + mi * 16 + lr) * 64 + kk * 32 + g * 8);
#pragma unroll
            for (int ni = 0; ni < 4; ni++)
                bfv[ni] = *(const bf16x8*)(Bs + (wc * 64 + ni * 16 + lr) * 64 + kk * 32 + g * 8);
#pragma unroll
            for (int mi = 0; mi < 4; mi++)
#pragma unroll
                for (int ni = 0; ni < 4; ni++)
                    acc[mi][ni] = __builtin_amdgcn_mfma_f32_16x16x32_bf16(af[mi], bfv[ni], acc[mi][ni], 0, 0, 0);
        }
    }

#pragma unroll
    for (int mi = 0; mi < 4; mi++) {
#pragma unroll
        for (int ni = 0; ni < 4; ni++) {
#pragma unroll
            for (int r = 0; r < 4; r++) {
                int row = m0 + wr * 64 + mi * 16 + g * 4 + r;
                int col = n0 + wc * 64 + ni * 16 + lr;
                float val = acc[mi][ni][r];
                if (MODE == 1) {
                    int b = row >> 11, n = row & 2047;
                    int which = col >> 10, cc = col & 1023;
                    int h = cc >> 6, d = cc & 63;
                    unsigned short* dst = which == 0 ? q : (which == 1 ? kk_ : v);
                    if (which == 0) val *= 0.125f;  // SCALE = 64^-0.5
                    dst[((size_t)(b * 16 + h) * 2048 + n) * 64 + d] = f2bf(val);
                } else {
                    outf[(size_t)row * 1024 + col] = val + bias[col];
                }
            }
        }
    }
}

// ---------------- flash attention, swapped-QK^T / in-lane softmax -------------
// per (b,h): 4 waves x 16 q-rows, KV tile 64, K/V double-buffered in LDS,
// XOR-swizzled (16B-chunk ^= row&7), K via global_load_lds with pre-swizzled
// global source (rule #21), V via async reg-gather (T14), P packed b64 in LDS.
__global__ __launch_bounds__(256) void k_attn(
    const unsigned short* __restrict__ qb, const unsigned short* __restrict__ kb,
    const unsigned short* __restrict__ vb, unsigned short* __restrict__ ao) {
    __shared__ unsigned short Ks[2][64 * 64];
    __shared__ unsigned short Vs[2][64 * 64];
    __shared__ unsigned short Ps[4][16 * 64];
    const int tid = threadIdx.x;
    const int w = tid >> 6, l = tid & 63, g = l >> 4, lr = l & 15;
    const int bh = blockIdx.y, b = bh >> 4, h = bh & 15;
    const int q0 = blockIdx.x * 64 + w * 16;
    const unsigned short* qp = qb + (size_t)bh * 131072;
    const unsigned short* kp = kb + (size_t)bh * 131072;
    const unsigned short* vp = vb + (size_t)bh * 131072;
    unsigned short* Psw = (unsigned short*)Ps[w];

    // Q fragment (B-operand of swapped QK^T): Q[q=q0+lr][d=kk*32+g*8+j]
    bf16x8 qf[2];
#pragma unroll
    for (int kk = 0; kk < 2; kk++)
        qf[kk] = *(const bf16x8*)(qp + (q0 + lr) * 64 + kk * 32 + g * 8);

    f32x4 o_acc[4] = {};
    float m_r = -1e30f, l_r = 0.f;

    // V gather bases: lane loads column d=l, kv rows (w+4i)*8..+7
    const unsigned short* vg0 = vp + l + (size_t)(w * 8) * 64;
    const unsigned short* vg1 = vp + l + (size_t)((w + 4) * 8) * 64;

    u16x8 tva, tvb;
    // ---- prologue: stage tile 0 ----
#pragma unroll
    for (int jj = 0; jj < 8; jj++) { tva[jj] = vg0[jj * 64]; tvb[jj] = vg1[jj * 64]; }
    {
        int row = tid >> 3, sl = tid & 7;
        gload16(kp + (size_t)row * 64 + (sl ^ (row & 7)) * 8, (char*)Ks[0] + tid * 16);
        int c1 = 256 + tid; row = c1 >> 3; sl = c1 & 7;
        gload16(kp + (size_t)row * 64 + (sl ^ (row & 7)) * 8, (char*)Ks[0] + c1 * 16);
    }
    asm volatile("s_waitcnt vmcnt(2)" ::: "memory");
    *(u16x8*)((char*)Vs[0] + l * 128 + ((w ^ (l & 7)) * 16)) = tva;
    *(u16x8*)((char*)Vs[0] + l * 128 + (((w + 4) ^ (l & 7)) * 16)) = tvb;
    asm volatile("s_waitcnt vmcnt(0)" ::: "memory");
    __syncthreads();

    int cur = 0;
    for (int t = 0; t < 32; ++t) {
        const int nxt = cur ^ 1;
        const bool pre = (t < 31);
        if (pre) {
            const unsigned short* p0 = vg0 + (size_t)(t + 1) * 4096;
            const unsigned short* p1 = vg1 + (size_t)(t + 1) * 4096;
#pragma unroll
            for (int jj = 0; jj < 8; jj++) { tva[jj] = p0[jj * 64]; tvb[jj] = p1[jj * 64]; }
            int kv0 = (t + 1) * 64;
            int row = tid >> 3, sl = tid & 7;
            gload16(kp + (size_t)(kv0 + row) * 64 + (sl ^ (row & 7)) * 8, (char*)Ks[nxt] + tid * 16);
            int c1 = 256 + tid; row = c1 >> 3; sl = c1 & 7;
            // FIX (round 2 bug): upper-half K must load rows kv0+row, row in [32,64)
            gload16(kp + (size_t)(kv0 + row) * 64 + (sl ^ (row & 7)) * 8, (char*)Ks[nxt] + c1 * 16);
        }

        // ---- S^T = K x Q : lane holds P^T[kv=16ct+4g+r][q=q0+lr] ----
        f32x4 s_acc[4];
#pragma unroll
        for (int ct = 0; ct < 4; ct++) s_acc[ct] = (f32x4){0.f, 0.f, 0.f, 0.f};
        __builtin_amdgcn_s_setprio(1);
#pragma unroll
        for (int kk = 0; kk < 2; kk++) {
#pragma unroll
            for (int ct = 0; ct < 4; ct++) {
                bf16x8 kf = *(const bf16x8*)((char*)Ks[cur] + (16 * ct + lr) * 128 + (((4 * kk + g) ^ (lr & 7)) * 16));
                s_acc[ct] = __builtin_amdgcn_mfma_f32_16x16x32_bf16(kf, qf[kk], s_acc[ct], 0, 0, 0);
            }
        }
        __builtin_amdgcn_s_setprio(0);

        // ---- in-lane online softmax for q-row q0+lr ----
        float mx = fmaxf(fmaxf(fmaxf(s_acc[0][0], s_acc[0][1]), fmaxf(s_acc[0][2], s_acc[0][3])),
                         fmaxf(fmaxf(s_acc[1][0], s_acc[1][1]), fmaxf(s_acc[1][2], s_acc[1][3])));
        mx = fmaxf(mx, fmaxf(fmaxf(fmaxf(s_acc[2][0], s_acc[2][1]), fmaxf(s_acc[2][2], s_acc[2][3])),
                             fmaxf(fmaxf(s_acc[3][0], s_acc[3][1]), fmaxf(s_acc[3][2], s_acc[3][3]))));
        mx = fmaxf(mx, __shfl_xor(mx, 16));
        mx = fmaxf(mx, __shfl_xor(mx, 32));
        float mn = fmaxf(m_r, mx);
        float fac = __expf(m_r - mn);
        m_r = mn;
        float ssum = 0.f;
#pragma unroll
        for (int ct = 0; ct < 4; ct++)
#pragma unroll
            for (int r = 0; r < 4; r++) {
                float p = __expf(s_acc[ct][r] - mn);
                s_acc[ct][r] = p;
                ssum += p;
            }
        ssum += __shfl_xor(ssum, 16);
        ssum += __shfl_xor(ssum, 32);
        l_r = l_r * fac + ssum;
        float facr[4];
#pragma unroll
        for (int r = 0; r < 4; r++) facr[r] = __shfl(fac, 4 * g + r, 16);
#pragma unroll
        for (int ct = 0; ct < 4; ct++) {
            o_acc[ct][0] *= facr[0]; o_acc[ct][1] *= facr[1];
            o_acc[ct][2] *= facr[2]; o_acc[ct][3] *= facr[3];
        }

        // ---- finish async V stage for next tile ----
        if (pre) {
            asm volatile("s_waitcnt vmcnt(2)" ::: "memory");
            *(u16x8*)((char*)Vs[nxt] + l * 128 + ((w ^ (l & 7)) * 16)) = tva;
            *(u16x8*)((char*)Vs[nxt] + l * 128 + (((w + 4) ^ (l & 7)) * 16)) = tvb;
        }

        // ---- write P (packed, swizzled): logical Ps[lr][16ct+4g + 0..3] ----
#pragma unroll
        for (int ct = 0; ct < 4; ct++) {
            u32x2 pw;
            pw[0] = pack2bf(s_acc[ct][0], s_acc[ct][1]);
            pw[1] = pack2bf(s_acc[ct][2], s_acc[ct][3]);
            *(u32x2*)((char*)Psw + lr * 128 + (((2 * ct + (g >> 1)) ^ (lr & 7)) * 16) + (g & 1) * 8) = pw;
        }
        asm volatile("s_waitcnt lgkmcnt(0)" ::: "memory");
        __builtin_amdgcn_sched_barrier(0);

        // ---- O += P V ----
        __builtin_amdgcn_s_setprio(1);
#pragma unroll
        for (int kk = 0; kk < 2; kk++) {
            bf16x8 pf = *(const bf16x8*)((char*)Psw + lr * 128 + (((4 * kk + g) ^ (lr & 7)) * 16));
#pragma unroll
            for (int ct = 0; ct < 4; ct++) {
                bf16x8 vf = *(const bf16x8*)((char*)Vs[cur] + (16 * ct + lr) * 128 + (((4 * kk + g) ^ (lr & 7)) * 16));
                o_acc[ct] = __builtin_amdgcn_mfma_f32_16x16x32_bf16(pf, vf, o_acc[ct], 0, 0, 0);
            }
        }
        __builtin_amdgcn_s_setprio(0);
        asm volatile("s_waitcnt vmcnt(0)" ::: "memory");
        __syncthreads();
        cur = nxt;
    }

    // ---- epilogue ----
    float ldiv[4];
#pragma unroll
    for (int r = 0; r < 4; r++) ldiv[r] = __shfl(l_r, 4 * g + r, 16);
#pragma unroll
    for (int ct = 0; ct < 4; ct++)
#pragma unroll
        for (int r = 0; r < 4; r++) {
            float o = o_acc[ct][r] / ldiv[r];
            int qrow = q0 + g * 4 + r;
            ao[((size_t)b * 2048 + qrow) * 1024 + h * 64 + ct * 16 + lr] = f2bf(o);
        }
}

extern "C" void kernel_launch(void* const* d_in, const int* in_sizes, int n_in,
                              void* d_out, int out_size, void* d_ws, size_t ws_size,
                              hipStream_t stream) {
    (void)in_sizes; (void)n_in; (void)out_size; (void)ws_size;
    const float* x      = (const float*)d_in[0];
    const float* w_qkv  = (const float*)d_in[1];
    const float* w_proj = (const float*)d_in[2];
    const float* b_proj = (const float*)d_in[3];
    float* out = (float*)d_out;
    char* ws = (char*)d_ws;

    // workspace layout (bytes); ao aliases xb (xb dead after GEMM1)
    unsigned short* xb     = (unsigned short*)(ws);             // [4096][1024] bf16
    unsigned short* ao     = (unsigned short*)(ws);             // [4096][1024] bf16 (alias)
    unsigned short* wqkvT  = (unsigned short*)(ws + 8388608);   // [3072][1024] bf16
    unsigned short* wprojT = (unsigned short*)(ws + 14680064);  // [1024][1024] bf16
    unsigned short* qb     = (unsigned short*)(ws + 16777216);  // [2][16][2048][64] bf16
    unsigned short* kb     = (unsigned short*)(ws + 25165824);
    unsigned short* vb     = (unsigned short*)(ws + 33554432);

    k_cvt<<<2048, 256, 0, stream>>>(x, xb, 1048576);
    k_transpose<<<dim3(48, 16), 256, 0, stream>>>(w_qkv, wqkvT, 3072);
    k_transpose<<<dim3(16, 16), 256, 0, stream>>>(w_proj, wprojT, 1024);
    k_gemm<1><<<dim3(24, 32), 256, 0, stream>>>(xb, wqkvT, 1024, qb, kb, vb, nullptr, nullptr);
    k_attn<<<dim3(32, 32), 256, 0, stream>>>(qb, kb, vb, ao);
    k_gemm<3><<<dim3(8, 32), 256, 0, stream>>>(ao, wprojT, 1024, nullptr, nullptr, nullptr, b_proj, out);
}

// Round 4
// 166.138 us; speedup vs baseline: 1.2716x; 1.0379x over previous
//
#include <hip/hip_runtime.h>
#include <stdint.h>

typedef float f32x4 __attribute__((ext_vector_type(4)));
typedef __bf16 bf16x8 __attribute__((ext_vector_type(8)));
typedef unsigned int u32x4 __attribute__((ext_vector_type(4)));
typedef unsigned int u32x2 __attribute__((ext_vector_type(2)));
typedef unsigned short u16x4 __attribute__((ext_vector_type(4)));
typedef unsigned short u16x8 __attribute__((ext_vector_type(8)));

#define DEV __device__ __forceinline__

// SCALE * log2(e): softmax computed base-2 (exact-equivalent, saves a mul per exp)
#define QSCALE_LOG2E 0.18033688011112042f

// round-to-nearest-even f32 -> bf16 bits (manual; used in mem-bound kernels)
DEV unsigned short f2bf(float f) {
    unsigned u = __builtin_bit_cast(unsigned, f);
    u += 0x7fffu + ((u >> 16) & 1u);
    return (unsigned short)(u >> 16);
}

// native cast path: compiler emits v_cvt_pk_bf16_f32 for pairs (RNE)
DEV unsigned pack2bf(float a, float b) {
    unsigned short ua = __builtin_bit_cast(unsigned short, (__bf16)a);
    unsigned short ub = __builtin_bit_cast(unsigned short, (__bf16)b);
    return (unsigned)ua | ((unsigned)ub << 16);
}

// async global->LDS, 16B per lane. LDS dst must be wave-uniform-base + lane*16.
DEV void gload16(const void* g, void* l) {
    __builtin_amdgcn_global_load_lds(
        (const __attribute__((address_space(1))) unsigned int*)(uintptr_t)g,
        (__attribute__((address_space(3))) unsigned int*)(unsigned int)(uintptr_t)l,
        16, 0, 0);
}

// ---------------- fp32 -> bf16 elementwise ----------------
__global__ void k_cvt(const float* __restrict__ in, unsigned short* __restrict__ out, int n4) {
    int i = blockIdx.x * 256 + threadIdx.x;
    int st = gridDim.x * 256;
    for (; i < n4; i += st) {
        f32x4 v = *(const f32x4*)(in + (size_t)i * 4);
        u16x4 o;
        o[0] = f2bf(v[0]); o[1] = f2bf(v[1]); o[2] = f2bf(v[2]); o[3] = f2bf(v[3]);
        *(u16x4*)(out + (size_t)i * 4) = o;
    }
}

// ---------------- fp32 [1024][Nc] -> bf16 [Nc][1024] transpose ----------------
__global__ void k_transpose(const float* __restrict__ in, unsigned short* __restrict__ out, int Nc) {
    __shared__ unsigned short tl[64][68];
    int n0 = blockIdx.x * 64, k0 = blockIdx.y * 64;
#pragma unroll
    for (int i = 0; i < 16; i++) {
        int idx = i * 256 + threadIdx.x;
        int kr = idx >> 6, nc = idx & 63;
        tl[kr][nc] = f2bf(in[(size_t)(k0 + kr) * Nc + n0 + nc]);
    }
    __syncthreads();
#pragma unroll
    for (int i = 0; i < 8; i++) {
        int idx = i * 256 + threadIdx.x;
        int nr = idx >> 5, kp2 = idx & 31;
        unsigned vv = (unsigned)tl[kp2 * 2][nr] | ((unsigned)tl[kp2 * 2 + 1][nr] << 16);
        *(unsigned*)(out + (size_t)(n0 + nr) * 1024 + k0 + kp2 * 2) = vv;
    }
}

// ---------------- GEMM: C[M][N] = A[M][K] * Bt[N][K]^T  (bf16 in, fp32 acc) ----
// MODE 1: scatter q (scaled by SCALE*log2e) / k to [B][H][N][D]; V TRANSPOSED
//         to vT [B][H][D][N] (u16x4 stores, 4 consecutive n per thread)
// MODE 3: out fp32 = C + bias (N fixed 1024)
template <int MODE>
__global__ __launch_bounds__(256) void k_gemm(
    const unsigned short* __restrict__ A, const unsigned short* __restrict__ Bt, int K,
    unsigned short* __restrict__ q, unsigned short* __restrict__ kk_,
    unsigned short* __restrict__ vT, const float* __restrict__ bias,
    float* __restrict__ outf) {
    __shared__ unsigned short As[128 * 64];
    __shared__ unsigned short Bs[128 * 64];
    const int tid = threadIdx.x;
    const int w = tid >> 6, l = tid & 63, g = l >> 4, lr = l & 15;
    const int wr = w >> 1, wc = w & 1;
    const int m0 = blockIdx.y * 128, n0 = blockIdx.x * 128;
    f32x4 acc[4][4] = {};

    for (int k0 = 0; k0 < K; k0 += 64) {
        __syncthreads();
#pragma unroll
        for (int i = 0; i < 4; i++) {
            int c = i * 256 + tid;
            gload16(A + (size_t)(m0 + (c >> 3)) * K + k0 + (c & 7) * 8, (char*)As + c * 16);
            gload16(Bt + (size_t)(n0 + (c >> 3)) * K + k0 + (c & 7) * 8, (char*)Bs + c * 16);
        }
        __syncthreads();
#pragma unroll
        for (int kk = 0; kk < 2; kk++) {
            bf16x8 af[4], bfv[4];
#pragma unroll
            for (int mi = 0; mi < 4; mi++)
                af[mi] = *(const bf16x8*)(As + (wr * 64 + mi * 16 + lr) * 64 + kk * 32 + g * 8);
#pragma unroll
            for (int ni = 0; ni < 4; ni++)
                bfv[ni] = *(const bf16x8*)(Bs + (wc * 64 + ni * 16 + lr) * 64 + kk * 32 + g * 8);
#pragma unroll
            for (int mi = 0; mi < 4; mi++)
#pragma unroll
                for (int ni = 0; ni < 4; ni++)
                    acc[mi][ni] = __builtin_amdgcn_mfma_f32_16x16x32_bf16(af[mi], bfv[ni], acc[mi][ni], 0, 0, 0);
        }
    }

#pragma unroll
    for (int mi = 0; mi < 4; mi++) {
#pragma unroll
        for (int ni = 0; ni < 4; ni++) {
            if (MODE == 1) {
                int row0 = m0 + wr * 64 + mi * 16 + g * 4;   // 4-aligned, no b-crossing
                int col = n0 + wc * 64 + ni * 16 + lr;
                int b = row0 >> 11, nn = row0 & 2047;
                int which = col >> 10, cc = col & 1023;      // uniform per (wc,ni)
                int h = cc >> 6, d = cc & 63;
                if (which == 2) {
                    u16x4 pv;
#pragma unroll
                    for (int r = 0; r < 4; r++) pv[r] = f2bf(acc[mi][ni][r]);
                    *(u16x4*)&vT[((size_t)(b * 16 + h) * 64 + d) * 2048 + nn] = pv;
                } else {
                    unsigned short* dst = (which == 0) ? q : kk_;
                    const float sc = (which == 0) ? QSCALE_LOG2E : 1.f;
#pragma unroll
                    for (int r = 0; r < 4; r++)
                        dst[((size_t)(b * 16 + h) * 2048 + nn + r) * 64 + d] = f2bf(acc[mi][ni][r] * sc);
                }
            } else {
#pragma unroll
                for (int r = 0; r < 4; r++) {
                    int row = m0 + wr * 64 + mi * 16 + g * 4 + r;
                    int col = n0 + wc * 64 + ni * 16 + lr;
                    outf[(size_t)row * 1024 + col] = acc[mi][ni][r] + bias[col];
                }
            }
        }
    }
}

// ---------------- flash attention, swapped-QK^T / in-lane softmax -------------
// per (b,h): 4 waves x 16 q-rows, KV tile 64. K [kv][d] and V^T [d][kv] both
// staged via global_load_lds (XOR-swizzled source, rule #21), double-buffered.
// Softmax base-2 (q pre-scaled by SCALE*log2e). P packed via cvt_pk to LDS.
__global__ __launch_bounds__(256) void k_attn(
    const unsigned short* __restrict__ qb, const unsigned short* __restrict__ kb,
    const unsigned short* __restrict__ vTb, unsigned short* __restrict__ ao) {
    __shared__ unsigned short Ks[2][64 * 64];
    __shared__ unsigned short Vs[2][64 * 64];
    __shared__ unsigned short Ps[4][16 * 64];
    const int tid = threadIdx.x;
    const int w = tid >> 6, l = tid & 63, g = l >> 4, lr = l & 15;
    const int bh = blockIdx.y, b = bh >> 4, h = bh & 15;
    const int q0 = blockIdx.x * 64 + w * 16;
    const unsigned short* qp = qb + (size_t)bh * 131072;
    const unsigned short* kp = kb + (size_t)bh * 131072;
    const unsigned short* vTp = vTb + (size_t)bh * 131072;  // [64 d][2048 n]
    unsigned short* Psw = (unsigned short*)Ps[w];

    // Q fragment (B-operand of swapped QK^T): Q[q=q0+lr][d=kk*32+g*8+j]
    bf16x8 qf[2];
#pragma unroll
    for (int kk = 0; kk < 2; kk++)
        qf[kk] = *(const bf16x8*)(qp + (q0 + lr) * 64 + kk * 32 + g * 8);

    f32x4 o_acc[4] = {};
    float m_r = -1e30f, l_r = 0.f;

    // staging: chunk c in [0,512): row=c>>3, slot p=c&7; LDS linear dest,
    // global source pre-swizzled so read-side XOR (p^(row&7)) is consistent.
    const int r0 = tid >> 3, p0 = tid & 7;
    const int c1 = 256 + tid, r1 = c1 >> 3, p1 = c1 & 7;
    const int ko0 = (p0 ^ (r0 & 7)) * 8, ko1 = (p1 ^ (r1 & 7)) * 8;

    // ---- prologue: stage tile 0 ----
    gload16(kp + (size_t)r0 * 64 + ko0, (char*)Ks[0] + tid * 16);
    gload16(kp + (size_t)r1 * 64 + ko1, (char*)Ks[0] + c1 * 16);
    gload16(vTp + (size_t)r0 * 2048 + ko0, (char*)Vs[0] + tid * 16);
    gload16(vTp + (size_t)r1 * 2048 + ko1, (char*)Vs[0] + c1 * 16);
    asm volatile("s_waitcnt vmcnt(0)" ::: "memory");
    __syncthreads();

    int cur = 0;
    for (int t = 0; t < 32; ++t) {
        const int nxt = cur ^ 1;
        if (t < 31) {
            const int kv0 = (t + 1) * 64;
            gload16(kp + (size_t)(kv0 + r0) * 64 + ko0, (char*)Ks[nxt] + tid * 16);
            gload16(kp + (size_t)(kv0 + r1) * 64 + ko1, (char*)Ks[nxt] + c1 * 16);
            gload16(vTp + (size_t)r0 * 2048 + kv0 + ko0, (char*)Vs[nxt] + tid * 16);
            gload16(vTp + (size_t)r1 * 2048 + kv0 + ko1, (char*)Vs[nxt] + c1 * 16);
        }

        // ---- S^T = K x Q : lane holds P^T[kv=16ct+4g+r][q=q0+lr] ----
        f32x4 s_acc[4];
#pragma unroll
        for (int ct = 0; ct < 4; ct++) s_acc[ct] = (f32x4){0.f, 0.f, 0.f, 0.f};
        __builtin_amdgcn_s_setprio(1);
#pragma unroll
        for (int kk = 0; kk < 2; kk++) {
#pragma unroll
            for (int ct = 0; ct < 4; ct++) {
                bf16x8 kf = *(const bf16x8*)((char*)Ks[cur] + (16 * ct + lr) * 128 + (((4 * kk + g) ^ (lr & 7)) * 16));
                s_acc[ct] = __builtin_amdgcn_mfma_f32_16x16x32_bf16(kf, qf[kk], s_acc[ct], 0, 0, 0);
            }
        }
        __builtin_amdgcn_s_setprio(0);

        // ---- in-lane online softmax (base 2) for q-row q0+lr ----
        float m1 = fmaxf(fmaxf(s_acc[0][0], s_acc[0][1]), s_acc[0][2]);
        float m2 = fmaxf(fmaxf(s_acc[0][3], s_acc[1][0]), s_acc[1][1]);
        float m3 = fmaxf(fmaxf(s_acc[1][2], s_acc[1][3]), s_acc[2][0]);
        float m4 = fmaxf(fmaxf(s_acc[2][1], s_acc[2][2]), s_acc[2][3]);
        float m5 = fmaxf(fmaxf(s_acc[3][0], s_acc[3][1]), s_acc[3][2]);
        float mx = fmaxf(fmaxf(m1, m2), m3);
        mx = fmaxf(fmaxf(mx, m4), m5);
        mx = fmaxf(mx, s_acc[3][3]);
        mx = fmaxf(mx, __shfl_xor(mx, 16));
        mx = fmaxf(mx, __shfl_xor(mx, 32));
        float mn = fmaxf(m_r, mx);
        float fac = __builtin_amdgcn_exp2f(m_r - mn);
        m_r = mn;
        float ssum = 0.f;
#pragma unroll
        for (int ct = 0; ct < 4; ct++)
#pragma unroll
            for (int r = 0; r < 4; r++) {
                float p = __builtin_amdgcn_exp2f(s_acc[ct][r] - mn);
                s_acc[ct][r] = p;
                ssum += p;
            }
        ssum += __shfl_xor(ssum, 16);
        ssum += __shfl_xor(ssum, 32);
        l_r = l_r * fac + ssum;
        float facr[4];
#pragma unroll
        for (int r = 0; r < 4; r++) facr[r] = __shfl(fac, 4 * g + r, 16);
#pragma unroll
        for (int ct = 0; ct < 4; ct++) {
            o_acc[ct][0] *= facr[0]; o_acc[ct][1] *= facr[1];
            o_acc[ct][2] *= facr[2]; o_acc[ct][3] *= facr[3];
        }

        // ---- write P (packed via cvt_pk, swizzled): logical Ps[lr][16ct+4g+0..3]
#pragma unroll
        for (int ct = 0; ct < 4; ct++) {
            u32x2 pw;
            pw[0] = pack2bf(s_acc[ct][0], s_acc[ct][1]);
            pw[1] = pack2bf(s_acc[ct][2], s_acc[ct][3]);
            *(u32x2*)((char*)Psw + lr * 128 + (((2 * ct + (g >> 1)) ^ (lr & 7)) * 16) + (g & 1) * 8) = pw;
        }
        asm volatile("s_waitcnt lgkmcnt(0)" ::: "memory");
        __builtin_amdgcn_sched_barrier(0);

        // ---- O += P V ----
        __builtin_amdgcn_s_setprio(1);
#pragma unroll
        for (int kk = 0; kk < 2; kk++) {
            bf16x8 pf = *(const bf16x8*)((char*)Psw + lr * 128 + (((4 * kk + g) ^ (lr & 7)) * 16));
#pragma unroll
            for (int ct = 0; ct < 4; ct++) {
                bf16x8 vf = *(const bf16x8*)((char*)Vs[cur] + (16 * ct + lr) * 128 + (((4 * kk + g) ^ (lr & 7)) * 16));
                o_acc[ct] = __builtin_amdgcn_mfma_f32_16x16x32_bf16(pf, vf, o_acc[ct], 0, 0, 0);
            }
        }
        __builtin_amdgcn_s_setprio(0);
        asm volatile("s_waitcnt vmcnt(0)" ::: "memory");
        __syncthreads();
        cur = nxt;
    }

    // ---- epilogue ----
    float ldiv[4];
#pragma unroll
    for (int r = 0; r < 4; r++) ldiv[r] = __shfl(l_r, 4 * g + r, 16);
#pragma unroll
    for (int ct = 0; ct < 4; ct++)
#pragma unroll
        for (int r = 0; r < 4; r++) {
            float o = o_acc[ct][r] / ldiv[r];
            int qrow = q0 + g * 4 + r;
            ao[((size_t)b * 2048 + qrow) * 1024 + h * 64 + ct * 16 + lr] = f2bf(o);
        }
}

extern "C" void kernel_launch(void* const* d_in, const int* in_sizes, int n_in,
                              void* d_out, int out_size, void* d_ws, size_t ws_size,
                              hipStream_t stream) {
    (void)in_sizes; (void)n_in; (void)out_size; (void)ws_size;
    const float* x      = (const float*)d_in[0];
    const float* w_qkv  = (const float*)d_in[1];
    const float* w_proj = (const float*)d_in[2];
    const float* b_proj = (const float*)d_in[3];
    float* out = (float*)d_out;
    char* ws = (char*)d_ws;

    // workspace layout (bytes); ao aliases xb (xb dead after GEMM1)
    unsigned short* xb     = (unsigned short*)(ws);             // [4096][1024] bf16
    unsigned short* ao     = (unsigned short*)(ws);             // [4096][1024] bf16 (alias)
    unsigned short* wqkvT  = (unsigned short*)(ws + 8388608);   // [3072][1024] bf16
    unsigned short* wprojT = (unsigned short*)(ws + 14680064);  // [1024][1024] bf16
    unsigned short* qb     = (unsigned short*)(ws + 16777216);  // [2][16][2048][64] bf16
    unsigned short* kb     = (unsigned short*)(ws + 25165824);  // [2][16][2048][64] bf16
    unsigned short* vTb    = (unsigned short*)(ws + 33554432);  // [2][16][64][2048] bf16

    k_cvt<<<2048, 256, 0, stream>>>(x, xb, 1048576);
    k_transpose<<<dim3(48, 16), 256, 0, stream>>>(w_qkv, wqkvT, 3072);
    k_transpose<<<dim3(16, 16), 256, 0, stream>>>(w_proj, wprojT, 1024);
    k_gemm<1><<<dim3(24, 32), 256, 0, stream>>>(xb, wqkvT, 1024, qb, kb, vTb, nullptr, nullptr);
    k_attn<<<dim3(32, 32), 256, 0, stream>>>(qb, kb, vTb, ao);
    k_gemm<3><<<dim3(8, 32), 256, 0, stream>>>(ao, wprojT, 1024, nullptr, nullptr, nullptr, b_proj, out);
}

// Round 5
// 165.337 us; speedup vs baseline: 1.2778x; 1.0048x over previous
//
#include <hip/hip_runtime.h>
#include <stdint.h>

typedef float f32x4 __attribute__((ext_vector_type(4)));
typedef float f32x16 __attribute__((ext_vector_type(16)));
typedef __bf16 bf16x8 __attribute__((ext_vector_type(8)));
typedef unsigned int u32x4 __attribute__((ext_vector_type(4)));
typedef unsigned short u16x4 __attribute__((ext_vector_type(4)));

#define DEV __device__ __forceinline__

// SCALE * log2(e): softmax computed base-2 (exact-equivalent)
#define QSCALE_LOG2E 0.18033688011112042f

// round-to-nearest-even f32 -> bf16 bits
DEV unsigned short f2bf(float f) {
    unsigned u = __builtin_bit_cast(unsigned, f);
    u += 0x7fffu + ((u >> 16) & 1u);
    return (unsigned short)(u >> 16);
}

// native cast path: compiler emits v_cvt_pk_bf16_f32 for pairs (RNE)
DEV unsigned pack2bf(float a, float b) {
    unsigned short ua = __builtin_bit_cast(unsigned short, (__bf16)a);
    unsigned short ub = __builtin_bit_cast(unsigned short, (__bf16)b);
    return (unsigned)ua | ((unsigned)ub << 16);
}

// lane i <-> lane i^32 pairwise exchange of two registers (gfx950)
DEV void pswap(unsigned& a, unsigned& b) {
    asm volatile("v_permlane32_swap_b32 %0, %1" : "+v"(a), "+v"(b));
}

// async global->LDS, 16B per lane. LDS dst must be wave-uniform-base + lane*16.
DEV void gload16(const void* g, void* l) {
    __builtin_amdgcn_global_load_lds(
        (const __attribute__((address_space(1))) unsigned int*)(uintptr_t)g,
        (__attribute__((address_space(3))) unsigned int*)(unsigned int)(uintptr_t)l,
        16, 0, 0);
}

// ---------------- fp32 -> bf16 elementwise ----------------
__global__ void k_cvt(const float* __restrict__ in, unsigned short* __restrict__ out, int n4) {
    int i = blockIdx.x * 256 + threadIdx.x;
    int st = gridDim.x * 256;
    for (; i < n4; i += st) {
        f32x4 v = *(const f32x4*)(in + (size_t)i * 4);
        u16x4 o;
        o[0] = f2bf(v[0]); o[1] = f2bf(v[1]); o[2] = f2bf(v[2]); o[3] = f2bf(v[3]);
        *(u16x4*)(out + (size_t)i * 4) = o;
    }
}

// ---------------- fp32 [1024][Nc] -> bf16 [Nc][1024] transpose ----------------
__global__ void k_transpose(const float* __restrict__ in, unsigned short* __restrict__ out, int Nc) {
    __shared__ unsigned short tl[64][68];
    int n0 = blockIdx.x * 64, k0 = blockIdx.y * 64;
#pragma unroll
    for (int i = 0; i < 16; i++) {
        int idx = i * 256 + threadIdx.x;
        int kr = idx >> 6, nc = idx & 63;
        tl[kr][nc] = f2bf(in[(size_t)(k0 + kr) * Nc + n0 + nc]);
    }
    __syncthreads();
#pragma unroll
    for (int i = 0; i < 8; i++) {
        int idx = i * 256 + threadIdx.x;
        int nr = idx >> 5, kp2 = idx & 31;
        unsigned vv = (unsigned)tl[kp2 * 2][nr] | ((unsigned)tl[kp2 * 2 + 1][nr] << 16);
        *(unsigned*)(out + (size_t)(n0 + nr) * 1024 + k0 + kp2 * 2) = vv;
    }
}

// ---------------- GEMM: C[M][N] = A[M][K] * Bt[N][K]^T  (bf16 in, fp32 acc) ----
// MODE 1: scatter q (scaled by SCALE*log2e) / k to [B][H][N][D]; V TRANSPOSED
//         to vT [B][H][D][N] (u16x4 stores)
// MODE 3: out fp32 = C + bias (N fixed 1024)
template <int MODE>
__global__ __launch_bounds__(256) void k_gemm(
    const unsigned short* __restrict__ A, const unsigned short* __restrict__ Bt, int K,
    unsigned short* __restrict__ q, unsigned short* __restrict__ kk_,
    unsigned short* __restrict__ vT, const float* __restrict__ bias,
    float* __restrict__ outf) {
    __shared__ unsigned short As[128 * 64];
    __shared__ unsigned short Bs[128 * 64];
    const int tid = threadIdx.x;
    const int w = tid >> 6, l = tid & 63, g = l >> 4, lr = l & 15;
    const int wr = w >> 1, wc = w & 1;
    const int m0 = blockIdx.y * 128, n0 = blockIdx.x * 128;
    f32x4 acc[4][4] = {};

    for (int k0 = 0; k0 < K; k0 += 64) {
        __syncthreads();
#pragma unroll
        for (int i = 0; i < 4; i++) {
            int c = i * 256 + tid;
            gload16(A + (size_t)(m0 + (c >> 3)) * K + k0 + (c & 7) * 8, (char*)As + c * 16);
            gload16(Bt + (size_t)(n0 + (c >> 3)) * K + k0 + (c & 7) * 8, (char*)Bs + c * 16);
        }
        __syncthreads();
#pragma unroll
        for (int kk = 0; kk < 2; kk++) {
            bf16x8 af[4], bfv[4];
#pragma unroll
            for (int mi = 0; mi < 4; mi++)
                af[mi] = *(const bf16x8*)(As + (wr * 64 + mi * 16 + lr) * 64 + kk * 32 + g * 8);
#pragma unroll
            for (int ni = 0; ni < 4; ni++)
                bfv[ni] = *(const bf16x8*)(Bs + (wc * 64 + ni * 16 + lr) * 64 + kk * 32 + g * 8);
#pragma unroll
            for (int mi = 0; mi < 4; mi++)
#pragma unroll
                for (int ni = 0; ni < 4; ni++)
                    acc[mi][ni] = __builtin_amdgcn_mfma_f32_16x16x32_bf16(af[mi], bfv[ni], acc[mi][ni], 0, 0, 0);
        }
    }

#pragma unroll
    for (int mi = 0; mi < 4; mi++) {
#pragma unroll
        for (int ni = 0; ni < 4; ni++) {
            if (MODE == 1) {
                int row0 = m0 + wr * 64 + mi * 16 + g * 4;   // 4-aligned, no b-crossing
                int col = n0 + wc * 64 + ni * 16 + lr;
                int b = row0 >> 11, nn = row0 & 2047;
                int which = col >> 10, cc = col & 1023;
                int h = cc >> 6, d = cc & 63;
                if (which == 2) {
                    u16x4 pv;
#pragma unroll
                    for (int r = 0; r < 4; r++) pv[r] = f2bf(acc[mi][ni][r]);
                    *(u16x4*)&vT[((size_t)(b * 16 + h) * 64 + d) * 2048 + nn] = pv;
                } else {
                    unsigned short* dst = (which == 0) ? q : kk_;
                    const float sc = (which == 0) ? QSCALE_LOG2E : 1.f;
#pragma unroll
                    for (int r = 0; r < 4; r++)
                        dst[((size_t)(b * 16 + h) * 2048 + nn + r) * 64 + d] = f2bf(acc[mi][ni][r] * sc);
                }
            } else {
#pragma unroll
                for (int r = 0; r < 4; r++) {
                    int row = m0 + wr * 64 + mi * 16 + g * 4 + r;
                    int col = n0 + wc * 64 + ni * 16 + lr;
                    outf[(size_t)row * 1024 + col] = acc[mi][ni][r] + bias[col];
                }
            }
        }
    }
}

// ---------------- flash attention, 32x32 swapped MFMA --------------------------
// 2 waves/block, each wave owns 32 q-rows; KV tile 64, double-buffered LDS.
// LDS chunk-major [p][row]: A-frag ds_read_b128 are contiguous-512B (0 conflict)
// AND global_load_lds destinations are linear. Swapped QK^T (mfma(K,Q)) puts a
// full q-row per lane -> lane-local softmax, no broadcasts. P->PV B-fragments
// via v_permlane32_swap (lane^32 exchange) -- no LDS round-trip, no fence.
__global__ __launch_bounds__(128) void k_attn(
    const unsigned short* __restrict__ qb, const unsigned short* __restrict__ kb,
    const unsigned short* __restrict__ vTb, unsigned short* __restrict__ ao) {
    __shared__ unsigned short Ks[2][4096];   // [8 p][64 row][8 elem] bf16 = 8KB each
    __shared__ unsigned short Vs[2][4096];
    const int tid = threadIdx.x;
    const int w = tid >> 6, l = tid & 63, l31 = l & 31, hf = l >> 5;
    const int bh = blockIdx.y, b = bh >> 4, h = bh & 15;
    const int qrow = blockIdx.x * 64 + w * 32 + l31;
    const unsigned short* qp = qb + (size_t)bh * 131072;
    const unsigned short* kp = kb + (size_t)bh * 131072;
    const unsigned short* vTp = vTb + (size_t)bh * 131072;  // [64 d][2048 n]

    // Q fragment (B-operand): B[k=d=dc*16+hf*8+j][col=q=l31]
    bf16x8 qf[4];
#pragma unroll
    for (int dc = 0; dc < 4; dc++)
        qf[dc] = *(const bf16x8*)(qp + (size_t)qrow * 64 + dc * 16 + hf * 8);

    f32x16 o_acc[2] = {};   // O^T[d = cd_row + 32*dt][q = l31]
    float m_r = -1e30f, l_r = 0.f;

    // staging: thread covers row = tid&63, chunks p = (tid>>6) + 2i, i=0..3
    const int row_s = tid & 63;
    const int pb = tid >> 6;

    // ---- prologue: stage tile 0 ----
#pragma unroll
    for (int i = 0; i < 4; i++)
        gload16(kp + (size_t)row_s * 64 + (pb + 2 * i) * 8, (char*)Ks[0] + (i * 128 + tid) * 16);
#pragma unroll
    for (int i = 0; i < 4; i++)
        gload16(vTp + (size_t)row_s * 2048 + (pb + 2 * i) * 8, (char*)Vs[0] + (i * 128 + tid) * 16);
    asm volatile("s_waitcnt vmcnt(0)" ::: "memory");
    __syncthreads();

    int cur = 0;
    for (int t = 0; t < 32; ++t) {
        const int nxt = cur ^ 1;
        if (t < 31) {
            const int kv0 = (t + 1) * 64;
#pragma unroll
            for (int i = 0; i < 4; i++)
                gload16(kp + (size_t)(kv0 + row_s) * 64 + (pb + 2 * i) * 8, (char*)Ks[nxt] + (i * 128 + tid) * 16);
#pragma unroll
            for (int i = 0; i < 4; i++)
                gload16(vTp + (size_t)row_s * 2048 + kv0 + (pb + 2 * i) * 8, (char*)Vs[nxt] + (i * 128 + tid) * 16);
        }

        // ---- S^T = K x Q : lane holds P^T[kv=(r&3)+8(r>>2)+4hf+32kt][q=l31] ----
        f32x16 s[2] = {};
        __builtin_amdgcn_s_setprio(1);
#pragma unroll
        for (int kt = 0; kt < 2; kt++)
#pragma unroll
            for (int dc = 0; dc < 4; dc++) {
                bf16x8 kf = *(const bf16x8*)((char*)Ks[cur] + (2 * dc + hf) * 1024 + (kt * 32 + l31) * 16);
                s[kt] = __builtin_amdgcn_mfma_f32_32x32x16_bf16(kf, qf[dc], s[kt], 0, 0, 0);
            }
        __builtin_amdgcn_s_setprio(0);

        // ---- lane-local online softmax (base 2) for q-row l31 ----
        float ma = fmaxf(fmaxf(s[0][0], s[0][1]), fmaxf(s[0][2], s[0][3]));
        float mb = fmaxf(fmaxf(s[0][4], s[0][5]), fmaxf(s[0][6], s[0][7]));
        float mc = fmaxf(fmaxf(s[0][8], s[0][9]), fmaxf(s[0][10], s[0][11]));
        float md = fmaxf(fmaxf(s[0][12], s[0][13]), fmaxf(s[0][14], s[0][15]));
        float me = fmaxf(fmaxf(s[1][0], s[1][1]), fmaxf(s[1][2], s[1][3]));
        float mf_ = fmaxf(fmaxf(s[1][4], s[1][5]), fmaxf(s[1][6], s[1][7]));
        float mg = fmaxf(fmaxf(s[1][8], s[1][9]), fmaxf(s[1][10], s[1][11]));
        float mh = fmaxf(fmaxf(s[1][12], s[1][13]), fmaxf(s[1][14], s[1][15]));
        float mx = fmaxf(fmaxf(fmaxf(ma, mb), fmaxf(mc, md)),
                         fmaxf(fmaxf(me, mf_), fmaxf(mg, mh)));
        mx = fmaxf(mx, __shfl_xor(mx, 32));
        // defer-max (T13): only rescale when the running max grew materially
        if (!__all(mx <= m_r + 8.f)) {
            float mn = fmaxf(m_r, mx);
            float fac = __builtin_amdgcn_exp2f(m_r - mn);
            m_r = mn;
            l_r *= fac;
#pragma unroll
            for (int r = 0; r < 16; r++) { o_acc[0][r] *= fac; o_acc[1][r] *= fac; }
        }
        float s0 = 0.f, s1 = 0.f, s2 = 0.f, s3 = 0.f;
#pragma unroll
        for (int kt = 0; kt < 2; kt++)
#pragma unroll
            for (int r = 0; r < 16; r += 4) {
                float p0 = __builtin_amdgcn_exp2f(s[kt][r] - m_r);
                float p1 = __builtin_amdgcn_exp2f(s[kt][r + 1] - m_r);
                float p2 = __builtin_amdgcn_exp2f(s[kt][r + 2] - m_r);
                float p3 = __builtin_amdgcn_exp2f(s[kt][r + 3] - m_r);
                s[kt][r] = p0; s[kt][r + 1] = p1; s[kt][r + 2] = p2; s[kt][r + 3] = p3;
                s0 += p0; s1 += p1; s2 += p2; s3 += p3;
            }
        float ssum = (s0 + s1) + (s2 + s3);
        ssum += __shfl_xor(ssum, 32);
        l_r += ssum;

        // ---- pack P to bf16, permlane32_swap -> PV B-frags, accumulate O^T ----
        __builtin_amdgcn_s_setprio(1);
#pragma unroll
        for (int kt = 0; kt < 2; kt++) {
            unsigned wd[8];
#pragma unroll
            for (int i = 0; i < 8; i++) wd[i] = pack2bf(s[kt][2 * i], s[kt][2 * i + 1]);
#pragma unroll
            for (int cl = 0; cl < 2; cl++) {
                unsigned b0 = wd[4 * cl + 0], b2 = wd[4 * cl + 2];
                unsigned b1 = wd[4 * cl + 1], b3 = wd[4 * cl + 3];
                pswap(b0, b2);
                pswap(b1, b3);
                u32x4 bw; bw[0] = b0; bw[1] = b1; bw[2] = b2; bw[3] = b3;
                bf16x8 pf = __builtin_bit_cast(bf16x8, bw);
                const int c = 2 * kt + cl;   // kv 16-chunk
#pragma unroll
                for (int dt = 0; dt < 2; dt++) {
                    bf16x8 vf = *(const bf16x8*)((char*)Vs[cur] + (2 * c + hf) * 1024 + (dt * 32 + l31) * 16);
                    o_acc[dt] = __builtin_amdgcn_mfma_f32_32x32x16_bf16(vf, pf, o_acc[dt], 0, 0, 0);
                }
            }
        }
        __builtin_amdgcn_s_setprio(0);

        asm volatile("s_waitcnt vmcnt(0)" ::: "memory");
        __syncthreads();
        cur = nxt;
    }

    // ---- epilogue: O^T row d per lane, 4-consecutive-d u16x4 stores ----
    float rl = 1.f / l_r;
    unsigned short* aop = ao + ((size_t)b * 2048 + qrow) * 1024 + h * 64;
#pragma unroll
    for (int dt = 0; dt < 2; dt++)
#pragma unroll
        for (int rg = 0; rg < 4; rg++) {
            u16x4 pv;
#pragma unroll
            for (int k = 0; k < 4; k++) pv[k] = f2bf(o_acc[dt][4 * rg + k] * rl);
            *(u16x4*)(aop + 8 * rg + 4 * hf + 32 * dt) = pv;
        }
}

extern "C" void kernel_launch(void* const* d_in, const int* in_sizes, int n_in,
                              void* d_out, int out_size, void* d_ws, size_t ws_size,
                              hipStream_t stream) {
    (void)in_sizes; (void)n_in; (void)out_size; (void)ws_size;
    const float* x      = (const float*)d_in[0];
    const float* w_qkv  = (const float*)d_in[1];
    const float* w_proj = (const float*)d_in[2];
    const float* b_proj = (const float*)d_in[3];
    float* out = (float*)d_out;
    char* ws = (char*)d_ws;

    // workspace layout (bytes); ao aliases xb (xb dead after GEMM1)
    unsigned short* xb     = (unsigned short*)(ws);             // [4096][1024] bf16
    unsigned short* ao     = (unsigned short*)(ws);             // [4096][1024] bf16 (alias)
    unsigned short* wqkvT  = (unsigned short*)(ws + 8388608);   // [3072][1024] bf16
    unsigned short* wprojT = (unsigned short*)(ws + 14680064);  // [1024][1024] bf16
    unsigned short* qb     = (unsigned short*)(ws + 16777216);  // [2][16][2048][64] bf16
    unsigned short* kb     = (unsigned short*)(ws + 25165824);  // [2][16][2048][64] bf16
    unsigned short* vTb    = (unsigned short*)(ws + 33554432);  // [2][16][64][2048] bf16

    k_cvt<<<2048, 256, 0, stream>>>(x, xb, 1048576);
    k_transpose<<<dim3(48, 16), 256, 0, stream>>>(w_qkv, wqkvT, 3072);
    k_transpose<<<dim3(16, 16), 256, 0, stream>>>(w_proj, wprojT, 1024);
    k_gemm<1><<<dim3(24, 32), 256, 0, stream>>>(xb, wqkvT, 1024, qb, kb, vTb, nullptr, nullptr);
    k_attn<<<dim3(32, 32), 128, 0, stream>>>(qb, kb, vTb, ao);
    k_gemm<3><<<dim3(8, 32), 256, 0, stream>>>(ao, wprojT, 1024, nullptr, nullptr, nullptr, b_proj, out);
}